// Round 1
// baseline (401.387 us; speedup 1.0000x reference)
//
#include <hip/hip_runtime.h>
#include <hip/hip_bf16.h>
#include <stdint.h>

#define B_   4
#define C_   256
#define C8_  32
#define HW_  4096
#define ROWS_ 320   // 32 Q rows + 32 K rows + 256 V rows

typedef __attribute__((ext_vector_type(8))) short  short8;
typedef __attribute__((ext_vector_type(4))) float  f32x4;

// ---- workspace layout (bytes) ----
// WallT  [256][320] f32 : composite weights, transposed (column-major rows)
// ball   [320] f32      : composite biases
// Qg     [B][HW][32] bf16
// Ktg    [B][HW][32] bf16   (K transposed: Kt[m][e] = k[e][m])
// Vg     [B][C][HW]  bf16
#define WT_OFF   0
#define BALL_OFF (256*320*4)                  // 327680
#define Q_OFF    (BALL_OFF + 1280)            // 328960
#define KT_OFF   (Q_OFF + B_*HW_*C8_*2)       // +1MB
#define V_OFF    (KT_OFF + B_*HW_*C8_*2)      // +1MB
// total = V_OFF + 8MB ~= 10.8 MB

__device__ __forceinline__ ushort f2bf(float f) {
    union { float f; uint32_t u; } v; v.f = f;
    uint32_t u = v.u;
    uint32_t r = u + 0x7fffu + ((u >> 16) & 1u);  // round-to-nearest-even
    return (ushort)(r >> 16);
}

// ---------------- kernel 1: fold conv into q/k/v weights ----------------
__global__ __launch_bounds__(256) void k_setup(
    const float* __restrict__ conv_w, const float* __restrict__ conv_b,
    const float* __restrict__ q_w, const float* __restrict__ q_b,
    const float* __restrict__ k_w, const float* __restrict__ k_b,
    const float* __restrict__ v_w, const float* __restrict__ v_b,
    float* __restrict__ wt, float* __restrict__ ball)
{
    int r = blockIdx.x;        // 0..319 composite row
    int c = threadIdx.x;       // 0..255 input channel
    const float* wrow;
    float bias;
    if (r < 32)       { wrow = q_w + r*32;      bias = q_b[r];      }
    else if (r < 64)  { wrow = k_w + (r-32)*32; bias = k_b[r-32];   }
    else              { wrow = v_w + (r-64)*32; bias = v_b[r-64];   }
    float acc = 0.f;
    #pragma unroll
    for (int d = 0; d < 32; ++d) acc += wrow[d] * conv_w[d*C_ + c];
    wt[c*ROWS_ + r] = acc;     // transposed store: WallT[c][r]
    if (c == 0) {
        float bb = bias;
        #pragma unroll
        for (int d = 0; d < 32; ++d) bb += wrow[d] * conv_b[d];
        ball[r] = bb;
    }
}

// ---------------- kernel 2: Q/Kt/V projection (VALU GEMM) ----------------
// grid = B * 16 ntiles * 5 rowgroups = 320 blocks, 256 threads
// wave owns 16 consecutive composite rows x 4 n-columns per lane
__global__ __launch_bounds__(256) void k_qkv(
    const float* __restrict__ x, const float* __restrict__ wt,
    const float* __restrict__ ball,
    ushort* __restrict__ qg, ushort* __restrict__ ktg, ushort* __restrict__ vg)
{
    int bidx = blockIdx.x;
    int g = bidx % 5; int tmp = bidx / 5;
    int ntile = tmp % 16; int b = tmp / 16;
    int t = threadIdx.x;
    int wave = t >> 6, lane = t & 63;
    int j0 = g*64 + wave*16;              // composite row base (wave-uniform)
    int n  = ntile*256 + lane*4;

    float acc[16][4];
    #pragma unroll
    for (int j = 0; j < 16; ++j)
        { acc[j][0]=0.f; acc[j][1]=0.f; acc[j][2]=0.f; acc[j][3]=0.f; }

    const float* xp = x + (size_t)b*C_*HW_ + n;
    for (int c = 0; c < C_; ++c) {
        float4 xv = *(const float4*)(xp + (size_t)c*HW_);
        const float* wc = wt + c*ROWS_ + j0;
        #pragma unroll
        for (int j = 0; j < 16; ++j) {
            float w = wc[j];
            acc[j][0] = fmaf(w, xv.x, acc[j][0]);
            acc[j][1] = fmaf(w, xv.y, acc[j][1]);
            acc[j][2] = fmaf(w, xv.z, acc[j][2]);
            acc[j][3] = fmaf(w, xv.w, acc[j][3]);
        }
    }

    if (j0 < 32) {              // Q rows: e = j0+j ; layout [B][HW][32]
        #pragma unroll
        for (int j = 0; j < 16; ++j) {
            int e = j0 + j; float bb = ball[e];
            #pragma unroll
            for (int nn = 0; nn < 4; ++nn)
                qg[((size_t)b*HW_ + n + nn)*C8_ + e] = f2bf(acc[j][nn] + bb);
        }
    } else if (j0 < 64) {       // K rows -> Kt layout [B][HW][32]
        #pragma unroll
        for (int j = 0; j < 16; ++j) {
            int e = j0 + j - 32; float bb = ball[j0 + j];
            #pragma unroll
            for (int nn = 0; nn < 4; ++nn)
                ktg[((size_t)b*HW_ + n + nn)*C8_ + e] = f2bf(acc[j][nn] + bb);
        }
    } else {                    // V rows: c = j0+j-64 ; layout [B][C][HW]
        #pragma unroll
        for (int j = 0; j < 16; ++j) {
            int cch = j0 + j - 64; float bb = ball[j0 + j];
            ushort4 pk;
            pk.x = f2bf(acc[j][0] + bb); pk.y = f2bf(acc[j][1] + bb);
            pk.z = f2bf(acc[j][2] + bb); pk.w = f2bf(acc[j][3] + bb);
            *(ushort4*)(vg + ((size_t)b*C_ + cch)*HW_ + n) = pk;
        }
    }
}

// ---------------- kernel 3: flash attention + epilogue ----------------
// grid = B*64 blocks, 256 threads (4 waves). wave owns 16 query rows.
// m-chunk = 64. S and PV via mfma_f32_16x16x32_bf16.
#define MC 64
#define L2E 1.4426950408889634f

__global__ __launch_bounds__(256) void k_attn(
    const ushort* __restrict__ qg, const ushort* __restrict__ ktg,
    const ushort* __restrict__ vg, const float* __restrict__ x,
    const float* __restrict__ gamma_p, float* __restrict__ out)
{
    __shared__ ushort v_lds[C_*72];        // V tile [256 c][64 m], stride 72 (16B-aligned rows)
    __shared__ ushort kt_lds[MC*40];       // Kt tile [64 m][32 e], stride 40
    __shared__ ushort p_lds[4][16*72];     // per-wave P transpose buffer [16 n][64 m]

    int blk = blockIdx.x;
    int b = blk >> 6;
    int tile = blk & 63;
    int t = threadIdx.x;
    int wave = t >> 6, lane = t & 63;
    int l15 = lane & 15, quad = lane >> 4;
    int nbase = tile*64 + wave*16;

    // Q fragment, A-layout: a[j] = Q[nbase + (lane&15)][quad*8 + j]
    short8 aq = *(const short8*)(qg + ((size_t)b*HW_ + nbase + l15)*C8_ + quad*8);

    f32x4 acc[16];
    #pragma unroll
    for (int i = 0; i < 16; ++i) acc[i] = (f32x4){0.f,0.f,0.f,0.f};
    float m_r[4] = {-1e30f,-1e30f,-1e30f,-1e30f};
    float l_r[4] = {0.f,0.f,0.f,0.f};

    const ushort* vb = vg + (size_t)b*C_*HW_;
    const ushort* kb = ktg + (size_t)b*HW_*C8_;

    for (int m0 = 0; m0 < HW_; m0 += MC) {
        // stage Kt tile: 64 rows x 32 e
        {
            int row = t >> 2, off = (t & 3) * 8;
            *(uint4*)(kt_lds + row*40 + off) =
                *(const uint4*)(kb + (size_t)(m0 + row)*C8_ + off);
        }
        // stage V tile: 256 rows x 64 m
        {
            const ushort* src = vb + (size_t)t*HW_ + m0;
            ushort* dst = v_lds + t*72;
            #pragma unroll
            for (int i = 0; i < 8; ++i)
                *(uint4*)(dst + i*8) = *(const uint4*)(src + i*8);
        }
        __syncthreads();

        // S = Q * Kt^T : 4 MFMAs of 16x16x32 over the 64-m chunk
        f32x4 s[4];
        #pragma unroll
        for (int tt = 0; tt < 4; ++tt) {
            short8 bk = *(const short8*)(kt_lds + (tt*16 + l15)*40 + quad*8);
            s[tt] = __builtin_amdgcn_mfma_f32_16x16x32_bf16(
                        aq, bk, (f32x4){0.f,0.f,0.f,0.f}, 0, 0, 0);
        }

        // per-row tile max (rows quad*4+r), reduce across 16 lanes of quad
        float mt[4];
        #pragma unroll
        for (int r = 0; r < 4; ++r) {
            float v0 = fmaxf(fmaxf(s[0][r], s[1][r]), fmaxf(s[2][r], s[3][r]));
            v0 = fmaxf(v0, __shfl_xor(v0, 1));
            v0 = fmaxf(v0, __shfl_xor(v0, 2));
            v0 = fmaxf(v0, __shfl_xor(v0, 4));
            v0 = fmaxf(v0, __shfl_xor(v0, 8));
            mt[r] = v0;
        }
        bool need = (mt[0] > m_r[0]) || (mt[1] > m_r[1]) ||
                    (mt[2] > m_r[2]) || (mt[3] > m_r[3]);
        if (__any(need)) {   // rare after warm-up: rescale accumulator
            #pragma unroll
            for (int r = 0; r < 4; ++r) {
                float mn = fmaxf(m_r[r], mt[r]);
                float alpha = exp2f((m_r[r] - mn) * L2E);
                m_r[r] = mn;
                l_r[r] *= alpha;
                #pragma unroll
                for (int cc = 0; cc < 16; ++cc) acc[cc][r] *= alpha;
            }
        }

        // P = exp(S - m), write to LDS in C-layout, accumulate row sums
        float ps[4] = {0.f,0.f,0.f,0.f};
        #pragma unroll
        for (int tt = 0; tt < 4; ++tt) {
            #pragma unroll
            for (int r = 0; r < 4; ++r) {
                float p = exp2f((s[tt][r] - m_r[r]) * L2E);
                ps[r] += p;
                p_lds[wave][(quad*4 + r)*72 + tt*16 + l15] = f2bf(p);
            }
        }
        #pragma unroll
        for (int r = 0; r < 4; ++r) {
            float v0 = ps[r];
            v0 += __shfl_xor(v0, 1);
            v0 += __shfl_xor(v0, 2);
            v0 += __shfl_xor(v0, 4);
            v0 += __shfl_xor(v0, 8);
            l_r[r] += v0;
        }

        // PV: read P back in A-layout, 16 channel-groups x 2 m-halves
        #pragma unroll
        for (int half = 0; half < 2; ++half) {
            short8 pa = *(const short8*)(&p_lds[wave][l15*72 + half*32 + quad*8]);
            #pragma unroll
            for (int cc = 0; cc < 16; ++cc) {
                short8 bv = *(const short8*)(v_lds + (cc*16 + l15)*72 + half*32 + quad*8);
                acc[cc] = __builtin_amdgcn_mfma_f32_16x16x32_bf16(pa, bv, acc[cc], 0, 0, 0);
            }
        }
        __syncthreads();
    }

    // epilogue: out = gamma * (acc/l) + x
    float g = gamma_p[0];
    float rl[4];
    #pragma unroll
    for (int r = 0; r < 4; ++r) rl[r] = 1.0f / l_r[r];
    const float* xb = x + (size_t)b*C_*HW_;
    float* ob = out + (size_t)b*C_*HW_;
    #pragma unroll
    for (int cc = 0; cc < 16; ++cc) {
        int c = cc*16 + l15;
        #pragma unroll
        for (int r = 0; r < 4; ++r) {
            int n = nbase + quad*4 + r;
            size_t idx = (size_t)c*HW_ + n;
            ob[idx] = g * acc[cc][r] * rl[r] + xb[idx];
        }
    }
}

extern "C" void kernel_launch(void* const* d_in, const int* in_sizes, int n_in,
                              void* d_out, int out_size, void* d_ws, size_t ws_size,
                              hipStream_t stream)
{
    const float* x      = (const float*)d_in[0];
    const float* conv_w = (const float*)d_in[1];
    const float* conv_b = (const float*)d_in[2];
    const float* q_w    = (const float*)d_in[3];
    const float* q_b    = (const float*)d_in[4];
    const float* k_w    = (const float*)d_in[5];
    const float* k_b    = (const float*)d_in[6];
    const float* v_w    = (const float*)d_in[7];
    const float* v_b    = (const float*)d_in[8];
    const float* gamma  = (const float*)d_in[9];
    float* out = (float*)d_out;

    char* ws = (char*)d_ws;
    float*  wt   = (float*)(ws + WT_OFF);
    float*  ball = (float*)(ws + BALL_OFF);
    ushort* qg   = (ushort*)(ws + Q_OFF);
    ushort* ktg  = (ushort*)(ws + KT_OFF);
    ushort* vg   = (ushort*)(ws + V_OFF);

    k_setup<<<ROWS_, 256, 0, stream>>>(conv_w, conv_b, q_w, q_b, k_w, k_b,
                                       v_w, v_b, wt, ball);
    k_qkv<<<B_*16*5, 256, 0, stream>>>(x, wt, ball, qg, ktg, vg);
    k_attn<<<B_*64, 256, 0, stream>>>(qg, ktg, vg, x, gamma, out);
}

// Round 2
// 280.086 us; speedup vs baseline: 1.4331x; 1.4331x over previous
//
#include <hip/hip_runtime.h>
#include <hip/hip_bf16.h>
#include <stdint.h>

#define B_   4
#define C_   256
#define C8_  32
#define HW_  4096
#define ROWS_ 320   // 32 Q + 32 K + 256 V composite rows

typedef __attribute__((ext_vector_type(8))) short  short8;
typedef __attribute__((ext_vector_type(4))) float  f32x4;

// ---- workspace layout (bytes) ----
#define WT_OFF   0
#define BALL_OFF (256*320*4)                  // 327680
#define Q_OFF    (BALL_OFF + 1280)            // 328960
#define KT_OFF   (Q_OFF + B_*HW_*C8_*2)
#define V_OFF    (KT_OFF + B_*HW_*C8_*2)
// total ~10.8 MB

__device__ __forceinline__ ushort f2bf(float f) {
    union { float f; uint32_t u; } v; v.f = f;
    uint32_t u = v.u;
    uint32_t r = u + 0x7fffu + ((u >> 16) & 1u);  // RNE
    return (ushort)(r >> 16);
}

// ---------------- kernel 1: fold conv into q/k/v weights ----------------
__global__ __launch_bounds__(256) void k_setup(
    const float* __restrict__ conv_w, const float* __restrict__ conv_b,
    const float* __restrict__ q_w, const float* __restrict__ q_b,
    const float* __restrict__ k_w, const float* __restrict__ k_b,
    const float* __restrict__ v_w, const float* __restrict__ v_b,
    float* __restrict__ wt, float* __restrict__ ball)
{
    int r = blockIdx.x;        // 0..319 composite row
    int c = threadIdx.x;       // 0..255 input channel
    const float* wrow;
    float bias;
    if (r < 32)       { wrow = q_w + r*32;      bias = q_b[r];      }
    else if (r < 64)  { wrow = k_w + (r-32)*32; bias = k_b[r-32];   }
    else              { wrow = v_w + (r-64)*32; bias = v_b[r-64];   }
    float acc = 0.f;
    #pragma unroll
    for (int d = 0; d < 32; ++d) acc += wrow[d] * conv_w[d*C_ + c];
    wt[c*ROWS_ + r] = acc;     // WallT[c][r]
    if (c == 0) {
        float bb = bias;
        #pragma unroll
        for (int d = 0; d < 32; ++d) bb += wrow[d] * conv_b[d];
        ball[r] = bb;
    }
}

// ---------------- kernel 2: Q/Kt/V projection (VALU GEMM, LDS weights) ----
// grid = B * 32 ntiles * 5 rowgroups = 640 blocks, 256 threads.
// Block stages its 64 composite-weight rows (x 256 c) into LDS once.
// Each wave: 16 rows; each lane: 2 n-columns; 8-deep x-load pipeline.
__global__ __launch_bounds__(256) void k_qkv(
    const float* __restrict__ x, const float* __restrict__ wt,
    const float* __restrict__ ball,
    ushort* __restrict__ qg, ushort* __restrict__ ktg, ushort* __restrict__ vg)
{
    __shared__ float w_lds[256*68];        // [c][64 rows], stride 68 (pad)

    int bidx = blockIdx.x;
    int g = bidx % 5; int tmp = bidx / 5;
    int ntile = tmp % 32; int b = tmp / 32;
    int t = threadIdx.x;
    int wave = t >> 6, lane = t & 63;
    int j0g = g*64;                        // block row base
    int jw  = wave*16;                     // wave row offset within 64
    int n   = ntile*128 + lane*2;

    // stage weights: thread t loads c-row t (64 floats)
    {
        const float* src = wt + (size_t)t*ROWS_ + j0g;
        float* dst = w_lds + t*68;
        #pragma unroll
        for (int k = 0; k < 16; ++k)
            *(float4*)(dst + k*4) = *(const float4*)(src + k*4);
    }
    __syncthreads();

    float acc[16][2];
    #pragma unroll
    for (int j = 0; j < 16; ++j) { acc[j][0]=0.f; acc[j][1]=0.f; }

    const float* xp = x + (size_t)b*C_*HW_ + n;
    float2 buf[8];
    #pragma unroll
    for (int u = 0; u < 8; ++u) buf[u] = *(const float2*)(xp + (size_t)u*HW_);

    for (int c0 = 0; c0 < C_; c0 += 8) {
        float2 cur[8];
        #pragma unroll
        for (int u = 0; u < 8; ++u) cur[u] = buf[u];
        if (c0 + 8 < C_) {
            #pragma unroll
            for (int u = 0; u < 8; ++u)
                buf[u] = *(const float2*)(xp + (size_t)(c0 + 8 + u)*HW_);
        }
        #pragma unroll
        for (int u = 0; u < 8; ++u) {
            const float* wc = w_lds + (c0 + u)*68 + jw;   // wave-uniform → broadcast
            #pragma unroll
            for (int j = 0; j < 16; ++j) {
                float w = wc[j];
                acc[j][0] = fmaf(w, cur[u].x, acc[j][0]);
                acc[j][1] = fmaf(w, cur[u].y, acc[j][1]);
            }
        }
    }

    int j0 = j0g + jw;
    if (j0 < 32) {              // Q rows -> [B][HW][32]
        #pragma unroll
        for (int j = 0; j < 16; ++j) {
            int e = j0 + j; float bb = ball[e];
            qg[((size_t)b*HW_ + n    )*C8_ + e] = f2bf(acc[j][0] + bb);
            qg[((size_t)b*HW_ + n + 1)*C8_ + e] = f2bf(acc[j][1] + bb);
        }
    } else if (j0 < 64) {       // K rows -> Kt [B][HW][32]
        #pragma unroll
        for (int j = 0; j < 16; ++j) {
            int e = j0 + j - 32; float bb = ball[j0 + j];
            ktg[((size_t)b*HW_ + n    )*C8_ + e] = f2bf(acc[j][0] + bb);
            ktg[((size_t)b*HW_ + n + 1)*C8_ + e] = f2bf(acc[j][1] + bb);
        }
    } else {                    // V rows -> [B][C][HW]
        #pragma unroll
        for (int j = 0; j < 16; ++j) {
            int cch = j0 + j - 64; float bb = ball[j0 + j];
            ushort2 pk;
            pk.x = f2bf(acc[j][0] + bb); pk.y = f2bf(acc[j][1] + bb);
            *(ushort2*)(vg + ((size_t)b*C_ + cch)*HW_ + n) = pk;
        }
    }
}

// ---------------- kernel 3: flash attention + epilogue ----------------
// grid = B * 64 tiles * 2 csplit = 512 blocks, 256 threads (4 waves).
// Wave owns 16 query rows; block owns 128 output channels.
// No online max (scores bounded, fp32 exp safe); l-reduce deferred to end.
#define MC 64
#define L2E 1.4426950408889634f

__global__ __launch_bounds__(256) void k_attn(
    const ushort* __restrict__ qg, const ushort* __restrict__ ktg,
    const ushort* __restrict__ vg, const float* __restrict__ x,
    const float* __restrict__ gamma_p, float* __restrict__ out)
{
    __shared__ ushort v_lds[128*72];       // V half-tile [128 c][64 m], stride 72
    __shared__ ushort kt_lds[MC*40];       // Kt tile [64 m][32 e], stride 40
    __shared__ ushort p_lds[4][16*72];     // per-wave P buffer [16 q][64 m]
    __shared__ float  l_lds[4][16];

    int blk = blockIdx.x;
    int b    = blk >> 7;
    int rest = blk & 127;
    int tile = rest >> 1;
    int cs   = rest & 1;                   // channel split: cs*128 .. +128
    int t = threadIdx.x;
    int wave = t >> 6, lane = t & 63;
    int l15 = lane & 15, quad = lane >> 4;
    int nbase = tile*64 + wave*16;

    // Q fragment (A-layout): a[j] = Q[nbase+l15][quad*8+j]
    short8 aq = *(const short8*)(qg + ((size_t)b*HW_ + nbase + l15)*C8_ + quad*8);

    f32x4 acc[8];
    #pragma unroll
    for (int i = 0; i < 8; ++i) acc[i] = (f32x4){0.f,0.f,0.f,0.f};
    float ps[4] = {0.f,0.f,0.f,0.f};       // partial l for q = quad*4+r

    const ushort* vb = vg + (size_t)b*C_*HW_ + (size_t)cs*128*HW_;
    const ushort* kb = ktg + (size_t)b*HW_*C8_;

    for (int m0 = 0; m0 < HW_; m0 += MC) {
        // stage Kt tile: 64 rows x 32 e (1 uint4/thread)
        {
            int row = t >> 2, off = (t & 3) * 8;
            *(uint4*)(kt_lds + row*40 + off) =
                *(const uint4*)(kb + (size_t)(m0 + row)*C8_ + off);
        }
        // stage V half-tile: 128 rows x 64 m (4 uint4/thread)
        {
            int row = t >> 1, hh = (t & 1)*32;
            const ushort* src = vb + (size_t)row*HW_ + m0 + hh;
            ushort* dst = v_lds + row*72 + hh;
            #pragma unroll
            for (int i = 0; i < 4; ++i)
                *(uint4*)(dst + i*8) = *(const uint4*)(src + i*8);
        }
        __syncthreads();

        // S = Q·Kt^T : 4 MFMAs
        f32x4 s[4];
        #pragma unroll
        for (int tt = 0; tt < 4; ++tt) {
            short8 bk = *(const short8*)(kt_lds + (tt*16 + l15)*40 + quad*8);
            s[tt] = __builtin_amdgcn_mfma_f32_16x16x32_bf16(
                        aq, bk, (f32x4){0.f,0.f,0.f,0.f}, 0, 0, 0);
        }

        // P = exp(S) (fixed max = 0), write LDS in C-layout, local l accumulate
        #pragma unroll
        for (int tt = 0; tt < 4; ++tt) {
            #pragma unroll
            for (int r = 0; r < 4; ++r) {
                float p = exp2f(s[tt][r] * L2E);
                ps[r] += p;
                p_lds[wave][(quad*4 + r)*72 + tt*16 + l15] = f2bf(p);
            }
        }

        // PV: A = V (rows=channels), B = P^T (cols=queries) → coalesced D
        #pragma unroll
        for (int half = 0; half < 2; ++half) {
            short8 pb = *(const short8*)(&p_lds[wave][l15*72 + half*32 + quad*8]);
            #pragma unroll
            for (int cc = 0; cc < 8; ++cc) {
                short8 av = *(const short8*)(v_lds + (cc*16 + l15)*72 + half*32 + quad*8);
                acc[cc] = __builtin_amdgcn_mfma_f32_16x16x32_bf16(av, pb, acc[cc], 0, 0, 0);
            }
        }
        __syncthreads();
    }

    // final l reduction across the 16 lanes of each quad-group
    #pragma unroll
    for (int r = 0; r < 4; ++r) {
        float v0 = ps[r];
        v0 += __shfl_xor(v0, 1);
        v0 += __shfl_xor(v0, 2);
        v0 += __shfl_xor(v0, 4);
        v0 += __shfl_xor(v0, 8);
        ps[r] = v0;
    }
    if (l15 == 0) {
        #pragma unroll
        for (int r = 0; r < 4; ++r) l_lds[wave][quad*4 + r] = ps[r];
    }
    __syncthreads();
    float rl = 1.0f / l_lds[wave][l15];    // l for query nbase + l15
    float g = gamma_p[0];

    // epilogue: out[c][n] = g*acc/l + x ; col = l15 = n → coalesced
    const float* xb = x + (size_t)b*C_*HW_;
    float* ob = out + (size_t)b*C_*HW_;
    int n = nbase + l15;
    #pragma unroll
    for (int cc = 0; cc < 8; ++cc) {
        #pragma unroll
        for (int r = 0; r < 4; ++r) {
            int c = cs*128 + cc*16 + quad*4 + r;
            size_t idx = (size_t)c*HW_ + n;
            ob[idx] = g * acc[cc][r] * rl + xb[idx];
        }
    }
}

extern "C" void kernel_launch(void* const* d_in, const int* in_sizes, int n_in,
                              void* d_out, int out_size, void* d_ws, size_t ws_size,
                              hipStream_t stream)
{
    const float* x      = (const float*)d_in[0];
    const float* conv_w = (const float*)d_in[1];
    const float* conv_b = (const float*)d_in[2];
    const float* q_w    = (const float*)d_in[3];
    const float* q_b    = (const float*)d_in[4];
    const float* k_w    = (const float*)d_in[5];
    const float* k_b    = (const float*)d_in[6];
    const float* v_w    = (const float*)d_in[7];
    const float* v_b    = (const float*)d_in[8];
    const float* gamma  = (const float*)d_in[9];
    float* out = (float*)d_out;

    char* ws = (char*)d_ws;
    float*  wt   = (float*)(ws + WT_OFF);
    float*  ball = (float*)(ws + BALL_OFF);
    ushort* qg   = (ushort*)(ws + Q_OFF);
    ushort* ktg  = (ushort*)(ws + KT_OFF);
    ushort* vg   = (ushort*)(ws + V_OFF);

    k_setup<<<ROWS_, 256, 0, stream>>>(conv_w, conv_b, q_w, q_b, k_w, k_b,
                                       v_w, v_b, wt, ball);
    k_qkv<<<B_*32*5, 256, 0, stream>>>(x, wt, ball, qg, ktg, vg);
    k_attn<<<B_*64*2, 256, 0, stream>>>(qg, ktg, vg, x, gamma, out);
}

// Round 4
// 206.133 us; speedup vs baseline: 1.9472x; 1.3588x over previous
//
#include <hip/hip_runtime.h>
#include <hip/hip_bf16.h>
#include <stdint.h>

#define B_   4
#define C_   256
#define C8_  32
#define HW_  4096
#define ROWS_ 320   // 32 Q + 32 K + 256 V composite rows
#define MS_  4      // m-split factor
#define L2E  1.4426950408889634f

typedef __attribute__((ext_vector_type(8)))  short  short8;
typedef __attribute__((ext_vector_type(8)))  ushort us8;
typedef __attribute__((ext_vector_type(16))) float  f32x16;

// ---- workspace layout (bytes) ----
#define WT_OFF    0
#define BALL_OFF  (256*320*4)
#define Q_OFF     (BALL_OFF + 1280)
#define KT_OFF    (Q_OFF  + B_*HW_*C8_*2)
#define V_OFF     (KT_OFF + B_*HW_*C8_*2)
#define PACC_OFF  (V_OFF  + B_*C_*HW_*2)            // ~10.8 MB so far
#define LPART_OFF (PACC_OFF + (size_t)MS_*B_*C_*HW_*2)  // +33.5 MB bf16 partials
// + MS_*B_*HW_*4 = 262 KB l partials  => total ~44.6 MB

__device__ __forceinline__ ushort f2bf(float f) {
    union { float f; uint32_t u; } v; v.f = f;
    uint32_t u = v.u;
    uint32_t r = u + 0x7fffu + ((u >> 16) & 1u);  // RNE
    return (ushort)(r >> 16);
}
__device__ __forceinline__ uint32_t pkbf(float a, float b) {
    return (uint32_t)f2bf(a) | ((uint32_t)f2bf(b) << 16);
}

// ---------------- kernel 1: fold conv into q/k/v weights ----------------
__global__ __launch_bounds__(256) void k_setup(
    const float* __restrict__ conv_w, const float* __restrict__ conv_b,
    const float* __restrict__ q_w, const float* __restrict__ q_b,
    const float* __restrict__ k_w, const float* __restrict__ k_b,
    const float* __restrict__ v_w, const float* __restrict__ v_b,
    float* __restrict__ wt, float* __restrict__ ball)
{
    int r = blockIdx.x;        // 0..319 composite row
    int c = threadIdx.x;       // 0..255 input channel
    const float* wrow;
    float bias;
    if (r < 32)       { wrow = q_w + r*32;      bias = q_b[r];      }
    else if (r < 64)  { wrow = k_w + (r-32)*32; bias = k_b[r-32];   }
    else              { wrow = v_w + (r-64)*32; bias = v_b[r-64];   }
    float acc = 0.f;
    #pragma unroll
    for (int d = 0; d < 32; ++d) acc += wrow[d] * conv_w[d*C_ + c];
    wt[c*ROWS_ + r] = acc;     // WallT[c][r]
    if (c == 0) {
        float bb = bias;
        #pragma unroll
        for (int d = 0; d < 32; ++d) bb += wrow[d] * conv_b[d];
        ball[r] = bb;
    }
}

// ---------------- kernel 2: Q/Kt/V projection ----------------
// grid = B * 16 ntiles * 10 rowgroups = 640 blocks, 256 threads.
// Wave handles 8 composite rows (scalar s_load weights), lane: 4 n-cols.
__global__ __launch_bounds__(256) void k_qkv(
    const float* __restrict__ x, const float* __restrict__ wt,
    const float* __restrict__ ball,
    ushort* __restrict__ qg, ushort* __restrict__ ktg, ushort* __restrict__ vg)
{
    int bidx = blockIdx.x;
    int g = bidx % 10; int tmp = bidx / 10;
    int ntile = tmp % 16; int b = tmp / 16;
    int t = threadIdx.x;
    int lane = t & 63;
    int j0 = __builtin_amdgcn_readfirstlane(g*32 + (t >> 6)*8);  // scalar row base
    int n = ntile*256 + lane*4;

    float acc[8][4];
    #pragma unroll
    for (int j = 0; j < 8; ++j)
        { acc[j][0]=0.f; acc[j][1]=0.f; acc[j][2]=0.f; acc[j][3]=0.f; }

    const float* xp = x + (size_t)b*C_*HW_ + n;
    float4 nbuf[4];
    #pragma unroll
    for (int u = 0; u < 4; ++u) nbuf[u] = *(const float4*)(xp + (size_t)u*HW_);

    for (int c0 = 0; c0 < C_; c0 += 4) {
        float4 cur[4];
        #pragma unroll
        for (int u = 0; u < 4; ++u) cur[u] = nbuf[u];
        if (c0 + 4 < C_) {
            #pragma unroll
            for (int u = 0; u < 4; ++u)
                nbuf[u] = *(const float4*)(xp + (size_t)(c0 + 4 + u)*HW_);
        }
        #pragma unroll
        for (int u = 0; u < 4; ++u) {
            const float* wr = wt + (size_t)(c0 + u)*ROWS_ + j0;  // scalar addr
            #pragma unroll
            for (int j = 0; j < 8; ++j) {
                float w = wr[j];
                acc[j][0] = fmaf(w, cur[u].x, acc[j][0]);
                acc[j][1] = fmaf(w, cur[u].y, acc[j][1]);
                acc[j][2] = fmaf(w, cur[u].z, acc[j][2]);
                acc[j][3] = fmaf(w, cur[u].w, acc[j][3]);
            }
        }
    }

    if (j0 < 32) {              // Q rows -> [B][HW][32]
        #pragma unroll
        for (int j = 0; j < 8; ++j) {
            int e = j0 + j; float bb = ball[e];
            #pragma unroll
            for (int nn = 0; nn < 4; ++nn)
                qg[((size_t)b*HW_ + n + nn)*C8_ + e] = f2bf(acc[j][nn] + bb);
        }
    } else if (j0 < 64) {       // K rows -> Kt [B][HW][32]
        #pragma unroll
        for (int j = 0; j < 8; ++j) {
            int e = j0 + j - 32; float bb = ball[j0 + j];
            #pragma unroll
            for (int nn = 0; nn < 4; ++nn)
                ktg[((size_t)b*HW_ + n + nn)*C8_ + e] = f2bf(acc[j][nn] + bb);
        }
    } else {                    // V rows -> [B][C][HW]
        #pragma unroll
        for (int j = 0; j < 8; ++j) {
            int cch = j0 + j - 64; float bb = ball[j0 + j];
            ushort4 pk;
            pk.x = f2bf(acc[j][0] + bb); pk.y = f2bf(acc[j][1] + bb);
            pk.z = f2bf(acc[j][2] + bb); pk.w = f2bf(acc[j][3] + bb);
            *(ushort4*)(vg + ((size_t)b*C_ + cch)*HW_ + n) = pk;
        }
    }
}

// ---------------- kernel 3: flash attention, m-split partials ----------------
// grid = B(4) x qb(16) x cs(2) x ms(4) = 512 blocks, 256 thr (4 waves).
// Block: 256 q x 128 c over a 1024-key m-range. Wave: 64 q x 128 c.
// S = mfma(Kt, Q) -> cols=q; P stays in regs (lane-half exchange via shfl);
// V,Kt staged to LDS in fragment order via global_load_lds (conflict-free).
__global__ __launch_bounds__(256, 2) void k_attn(
    const ushort* __restrict__ qg, const ushort* __restrict__ ktg,
    const ushort* __restrict__ vg,
    ushort* __restrict__ pacc, float* __restrict__ lpart)
{
    __shared__ ushort v_lds[2][16*512];   // 16 V frags (cfr*4+ks), 1KB each
    __shared__ ushort kt_lds[2][4*512];   // 4 Kt frags (kb*2+ks)

    int blk = blockIdx.x;
    int msid = blk & 3;
    int cs   = (blk >> 2) & 1;
    int qb   = (blk >> 3) & 15;
    int b    = blk >> 7;
    int t = threadIdx.x;
    int w = t >> 6, lane = t & 63;
    int l31 = lane & 31, h = lane >> 5;
    int qbase = qb*256 + w*64;
    int cbase = cs*128;
    int mbase = msid*1024;

    const ushort* kb_p = ktg + (size_t)b*HW_*C8_;
    const ushort* vb_p = vg  + (size_t)b*C_*HW_;

    // Q fragments (B-operand): lane l31 = q, regs = 8 consec e
    short8 qf[2][2];
    #pragma unroll
    for (int qfr = 0; qfr < 2; ++qfr)
        #pragma unroll
        for (int ks = 0; ks < 2; ++ks)
            qf[qfr][ks] = *(const short8*)(qg + ((size_t)b*HW_ + qbase + qfr*32 + l31)*C8_
                                           + ks*16 + h*8);

    f32x16 acc[2][4];
    #pragma unroll
    for (int i = 0; i < 2; ++i)
        #pragma unroll
        for (int j = 0; j < 4; ++j)
            acc[i][j] = (f32x16)(0.f);
    float lsum[2] = {0.f, 0.f};

    // ---- staging: wave w stages V frags (cfr=w, ks=0..3) + Kt frag w ----
    #define STAGE(buf, m0)                                                          \
    {                                                                               \
        _Pragma("unroll")                                                           \
        for (int ks = 0; ks < 4; ++ks) {                                            \
            const ushort* src = vb_p + (size_t)(cbase + w*32 + l31)*HW_             \
                                + (m0) + ks*16 + h*8;                               \
            __builtin_amdgcn_global_load_lds(                                       \
                (const __attribute__((address_space(1))) uint32_t*)src,             \
                (__attribute__((address_space(3))) uint32_t*)&v_lds[buf][(w*4+ks)*512], \
                16, 0, 0);                                                          \
        }                                                                           \
        {                                                                           \
            int kb = w >> 1, ks = w & 1;                                            \
            const ushort* src = kb_p + (size_t)((m0) + kb*32 + l31)*C8_             \
                                + ks*16 + h*8;                                      \
            __builtin_amdgcn_global_load_lds(                                       \
                (const __attribute__((address_space(1))) uint32_t*)src,             \
                (__attribute__((address_space(3))) uint32_t*)&kt_lds[buf][w*512],   \
                16, 0, 0);                                                          \
        }                                                                           \
    }

    STAGE(0, mbase)
    __syncthreads();

    int buf = 0;
    for (int it = 0; it < 16; ++it) {
        if (it + 1 < 16) STAGE(buf ^ 1, mbase + (it+1)*64)

        // Kt fragments for this chunk
        short8 ktf[2][2];
        #pragma unroll
        for (int kb = 0; kb < 2; ++kb)
            #pragma unroll
            for (int ks = 0; ks < 2; ++ks)
                ktf[kb][ks] = *(const short8*)(&kt_lds[buf][(kb*2+ks)*512 + lane*8]);

        // S tiles -> exp -> packed bf16 pairs in regs
        uint32_t up[4][8];   // [qfr*2+kb][8]
        #pragma unroll
        for (int qfr = 0; qfr < 2; ++qfr) {
            #pragma unroll
            for (int kb = 0; kb < 2; ++kb) {
                f32x16 s = (f32x16)(0.f);
                s = __builtin_amdgcn_mfma_f32_32x32x16_bf16(ktf[kb][0], qf[qfr][0], s, 0, 0, 0);
                s = __builtin_amdgcn_mfma_f32_32x32x16_bf16(ktf[kb][1], qf[qfr][1], s, 0, 0, 0);
                float e[16]; float tl = 0.f;
                #pragma unroll
                for (int r = 0; r < 16; ++r) {
                    e[r] = __builtin_amdgcn_exp2f(s[r] * L2E);
                    tl += e[r];
                }
                lsum[qfr] += tl;
                #pragma unroll
                for (int i = 0; i < 8; ++i)
                    up[qfr*2+kb][i] = pkbf(e[2*i], e[2*i+1]);
            }
        }

        // Build PV B-fragments: lane-half exchange (keys 4h..4h+3 pattern)
        short8 pf[2][4];   // [qfr][ks 0..3]
        #pragma unroll
        for (int qfr = 0; qfr < 2; ++qfr) {
            #pragma unroll
            for (int kb = 0; kb < 2; ++kb) {
                uint32_t* u = up[qfr*2+kb];
                uint32_t bpA = (uint32_t)__shfl_xor((int)(h ? u[0] : u[2]), 32);
                uint32_t bpB = (uint32_t)__shfl_xor((int)(h ? u[1] : u[3]), 32);
                uint32_t bpC = (uint32_t)__shfl_xor((int)(h ? u[4] : u[6]), 32);
                uint32_t bpD = (uint32_t)__shfl_xor((int)(h ? u[5] : u[7]), 32);
                union { uint32_t d[4]; short8 s8; } fe, fo;
                fe.d[0] = h ? bpA : u[0];  fe.d[1] = h ? bpB : u[1];
                fe.d[2] = h ? u[2] : bpA;  fe.d[3] = h ? u[3] : bpB;
                fo.d[0] = h ? bpC : u[4];  fo.d[1] = h ? bpD : u[5];
                fo.d[2] = h ? u[6] : bpC;  fo.d[3] = h ? u[7] : bpD;
                pf[qfr][kb*2 + 0] = fe.s8;
                pf[qfr][kb*2 + 1] = fo.s8;
            }
        }

        // PV: acc[qfr][cfr] += V(cfr,ks) * P(qfr,ks)
        #pragma unroll
        for (int ks = 0; ks < 4; ++ks) {
            #pragma unroll
            for (int cfr = 0; cfr < 4; ++cfr) {
                short8 vf = *(const short8*)(&v_lds[buf][(cfr*4+ks)*512 + lane*8]);
                acc[0][cfr] = __builtin_amdgcn_mfma_f32_32x32x16_bf16(vf, pf[0][ks], acc[0][cfr], 0, 0, 0);
                acc[1][cfr] = __builtin_amdgcn_mfma_f32_32x32x16_bf16(vf, pf[1][ks], acc[1][cfr], 0, 0, 0);
            }
        }
        __syncthreads();
        buf ^= 1;
    }

    // finalize l: add other lane-half's key contributions
    #pragma unroll
    for (int qfr = 0; qfr < 2; ++qfr) {
        union { float f; int i; } cv; cv.f = lsum[qfr];
        cv.i = __shfl_xor(cv.i, 32);
        lsum[qfr] += cv.f;
    }
    if (cs == 0 && h == 0) {
        #pragma unroll
        for (int qfr = 0; qfr < 2; ++qfr)
            lpart[(size_t)(msid*B_ + b)*HW_ + qbase + qfr*32 + l31] = lsum[qfr];
    }

    // store bf16 partial accumulators: [ms][b][c][q]
    #pragma unroll
    for (int qfr = 0; qfr < 2; ++qfr) {
        int q = qbase + qfr*32 + l31;
        #pragma unroll
        for (int cfr = 0; cfr < 4; ++cfr) {
            #pragma unroll
            for (int r = 0; r < 16; ++r) {
                int c = cbase + cfr*32 + (r & 3) + 8*(r >> 2) + 4*h;
                pacc[((size_t)(msid*B_ + b)*C_ + c)*HW_ + q] = f2bf(acc[qfr][cfr][r]);
            }
        }
    }
    #undef STAGE
}

// ---------------- kernel 4: combine partials + epilogue ----------------
// out = gamma * (sum_ms pacc) / (sum_ms lpart) + x
__global__ __launch_bounds__(256) void k_comb(
    const ushort* __restrict__ pacc, const float* __restrict__ lpart,
    const float* __restrict__ x, const float* __restrict__ gamma_p,
    float* __restrict__ out)
{
    int gid = blockIdx.x * 256 + threadIdx.x;   // one thread = 8 elements
    int q8 = gid & 511;
    int c  = (gid >> 9) & 255;
    int b  = gid >> 17;
    size_t base = ((size_t)b*C_ + c)*HW_ + q8*8;

    float sum[8];
    #pragma unroll
    for (int k = 0; k < 8; ++k) sum[k] = 0.f;
    float lt[8];
    #pragma unroll
    for (int k = 0; k < 8; ++k) lt[k] = 0.f;

    #pragma unroll
    for (int ms = 0; ms < MS_; ++ms) {
        const ushort* pp = pacc + ((size_t)(ms*B_ + b)*C_ + c)*HW_ + q8*8;
        us8 v = *(const us8*)pp;
        #pragma unroll
        for (int k = 0; k < 8; ++k) {
            union { uint32_t u; float f; } cv; cv.u = ((uint32_t)v[k]) << 16;
            sum[k] += cv.f;
        }
        const float* lp = lpart + (size_t)(ms*B_ + b)*HW_ + q8*8;
        float4 l0 = *(const float4*)lp;
        float4 l1 = *(const float4*)(lp + 4);
        lt[0] += l0.x; lt[1] += l0.y; lt[2] += l0.z; lt[3] += l0.w;
        lt[4] += l1.x; lt[5] += l1.y; lt[6] += l1.z; lt[7] += l1.w;
    }

    float g = gamma_p[0];
    float4 x0 = *(const float4*)(x + base);
    float4 x1 = *(const float4*)(x + base + 4);
    float4 o0, o1;
    o0.x = g*sum[0]/lt[0] + x0.x;  o0.y = g*sum[1]/lt[1] + x0.y;
    o0.z = g*sum[2]/lt[2] + x0.z;  o0.w = g*sum[3]/lt[3] + x0.w;
    o1.x = g*sum[4]/lt[4] + x1.x;  o1.y = g*sum[5]/lt[5] + x1.y;
    o1.z = g*sum[6]/lt[6] + x1.z;  o1.w = g*sum[7]/lt[7] + x1.w;
    *(float4*)(out + base)     = o0;
    *(float4*)(out + base + 4) = o1;
}

extern "C" void kernel_launch(void* const* d_in, const int* in_sizes, int n_in,
                              void* d_out, int out_size, void* d_ws, size_t ws_size,
                              hipStream_t stream)
{
    const float* x      = (const float*)d_in[0];
    const float* conv_w = (const float*)d_in[1];
    const float* conv_b = (const float*)d_in[2];
    const float* q_w    = (const float*)d_in[3];
    const float* q_b    = (const float*)d_in[4];
    const float* k_w    = (const float*)d_in[5];
    const float* k_b    = (const float*)d_in[6];
    const float* v_w    = (const float*)d_in[7];
    const float* v_b    = (const float*)d_in[8];
    const float* gamma  = (const float*)d_in[9];
    float* out = (float*)d_out;

    char* ws = (char*)d_ws;
    float*  wt    = (float*)(ws + WT_OFF);
    float*  ball  = (float*)(ws + BALL_OFF);
    ushort* qg    = (ushort*)(ws + Q_OFF);
    ushort* ktg   = (ushort*)(ws + KT_OFF);
    ushort* vg    = (ushort*)(ws + V_OFF);
    ushort* pacc  = (ushort*)(ws + PACC_OFF);
    float*  lpart = (float*)(ws + LPART_OFF);

    k_setup<<<ROWS_, 256, 0, stream>>>(conv_w, conv_b, q_w, q_b, k_w, k_b,
                                       v_w, v_b, wt, ball);
    k_qkv<<<B_*16*10, 256, 0, stream>>>(x, wt, ball, qg, ktg, vg);
    k_attn<<<512, 256, 0, stream>>>(qg, ktg, vg, pacc, lpart);
    k_comb<<<(B_*C_*HW_/8 + 255)/256, 256, 0, stream>>>(pacc, lpart, x, gamma, out);
}

// Round 5
// 186.400 us; speedup vs baseline: 2.1534x; 1.1059x over previous
//
#include <hip/hip_runtime.h>
#include <hip/hip_bf16.h>
#include <stdint.h>

#define B_   4
#define C_   256
#define C8_  32
#define HW_  4096
#define ROWS_ 320   // 32 Q + 32 K + 256 V composite rows
#define MS_  4      // m-split factor
#define L2E  1.4426950408889634f

typedef __attribute__((ext_vector_type(8)))  short  short8;
typedef __attribute__((ext_vector_type(8)))  ushort us8;
typedef __attribute__((ext_vector_type(16))) float  f32x16;

// ---- workspace layout (bytes) ----
#define WT_OFF    0                            // wbf: bf16 [320 r][256 c] = 160 KB
#define BALL_OFF  (256*320*4)
#define Q_OFF     (BALL_OFF + 1280)
#define KT_OFF    (Q_OFF  + B_*HW_*C8_*2)
#define V_OFF     (KT_OFF + B_*HW_*C8_*2)
#define PACC_OFF  (V_OFF  + B_*C_*HW_*2)
#define LPART_OFF (PACC_OFF + (size_t)MS_*B_*C_*HW_*2)
// total ~44.6 MB

__device__ __forceinline__ ushort f2bf(float f) {
    union { float f; uint32_t u; } v; v.f = f;
    uint32_t u = v.u;
    uint32_t r = u + 0x7fffu + ((u >> 16) & 1u);  // RNE
    return (ushort)(r >> 16);
}
// pack two fp32 -> two bf16 (truncation) in ONE v_perm_b32
__device__ __forceinline__ uint32_t pktr(float lo, float hi) {
    union { float f; uint32_t u; } a, b; a.f = lo; b.f = hi;
    return __builtin_amdgcn_perm(b.u, a.u, 0x07060302u);
}

// ---------------- kernel 1: fold conv into q/k/v weights (bf16) ----------
__global__ __launch_bounds__(256) void k_setup(
    const float* __restrict__ conv_w, const float* __restrict__ conv_b,
    const float* __restrict__ q_w, const float* __restrict__ q_b,
    const float* __restrict__ k_w, const float* __restrict__ k_b,
    const float* __restrict__ v_w, const float* __restrict__ v_b,
    ushort* __restrict__ wbf, float* __restrict__ ball)
{
    int r = blockIdx.x;        // 0..319 composite row
    int c = threadIdx.x;       // 0..255 input channel
    const float* wrow;
    float bias;
    if (r < 32)       { wrow = q_w + r*32;      bias = q_b[r];      }
    else if (r < 64)  { wrow = k_w + (r-32)*32; bias = k_b[r-32];   }
    else              { wrow = v_w + (r-64)*32; bias = v_b[r-64];   }
    float acc = 0.f;
    #pragma unroll
    for (int d = 0; d < 32; ++d) acc += wrow[d] * conv_w[d*C_ + c];
    float scale = (r < 32) ? L2E : 1.0f;       // fold log2(e) into Q
    wbf[r*C_ + c] = f2bf(acc * scale);
    if (c == 0) {
        float bb = bias;
        #pragma unroll
        for (int d = 0; d < 32; ++d) bb += wrow[d] * conv_b[d];
        ball[r] = bb * scale;
    }
}

// ---------------- kernel 2: Q/Kt/V projection via MFMA ----------------
// grid = B * 64 ntiles = 256 blocks, 320 threads (5 waves = 320 rows).
// Wave w: composite rows [w*64, w*64+64), 64 n-cols. No LDS: B-frags built
// from coalesced global dword loads of x + v_perm bf16 packing.
__global__ __launch_bounds__(320) void k_qkv(
    const float* __restrict__ x, const ushort* __restrict__ wbf,
    const float* __restrict__ ball,
    ushort* __restrict__ qg, ushort* __restrict__ ktg, ushort* __restrict__ vg)
{
    int blk = blockIdx.x;
    int b  = blk >> 6;
    int n0 = (blk & 63) * 64;
    int t = threadIdx.x;
    int w = t >> 6, lane = t & 63;
    int l31 = lane & 31, h = lane >> 5;

    f32x16 acc[2][2];   // [mi][ni]
    #pragma unroll
    for (int i = 0; i < 2; ++i)
        #pragma unroll
        for (int j = 0; j < 2; ++j)
            acc[i][j] = (f32x16)(0.f);

    const float* xb = x + (size_t)b*C_*HW_;
    const ushort* wrow0 = wbf + (size_t)(w*64 + l31)*C_ + h*8;       // mi=0 row
    const ushort* wrow1 = wrow0 + 32*C_;                              // mi=1 row

    #pragma unroll 2
    for (int kc = 0; kc < 16; ++kc) {          // K chunks of 16
        int k0 = kc*16;
        short8 a0 = *(const short8*)(wrow0 + k0);
        short8 a1 = *(const short8*)(wrow1 + k0);
        #pragma unroll
        for (int ni = 0; ni < 2; ++ni) {
            const float* xc = xb + (size_t)(k0 + h*8)*HW_ + n0 + ni*32 + l31;
            union { uint32_t d[4]; short8 s8; } bf;
            #pragma unroll
            for (int j2 = 0; j2 < 4; ++j2) {
                float f0 = xc[(size_t)(2*j2    )*HW_];
                float f1 = xc[(size_t)(2*j2 + 1)*HW_];
                bf.d[j2] = pktr(f0, f1);
            }
            acc[0][ni] = __builtin_amdgcn_mfma_f32_32x32x16_bf16(a0, bf.s8, acc[0][ni], 0, 0, 0);
            acc[1][ni] = __builtin_amdgcn_mfma_f32_32x32x16_bf16(a1, bf.s8, acc[1][ni], 0, 0, 0);
        }
    }

    // epilogue: bias + bf16 + store per destination layout
    #pragma unroll
    for (int mi = 0; mi < 2; ++mi) {
        int rowb = w*64 + mi*32;
        #pragma unroll
        for (int ni = 0; ni < 2; ++ni) {
            int n = n0 + ni*32 + l31;
            #pragma unroll
            for (int r = 0; r < 16; ++r) {
                int row = rowb + (r & 3) + 8*(r >> 2) + 4*h;
                float v = acc[mi][ni][r] + ball[row];
                ushort bv = f2bf(v);
                if (row < 32) {
                    qg[((size_t)b*HW_ + n)*C8_ + row] = bv;
                } else if (row < 64) {
                    ktg[((size_t)b*HW_ + n)*C8_ + (row - 32)] = bv;
                } else {
                    vg[((size_t)b*C_ + (row - 64))*HW_ + n] = bv;
                }
            }
        }
    }
}

// ---------------- kernel 3: flash attention, m-split partials ----------------
// grid = B(4) x qb(16) x cs(2) x ms(4) = 512 blocks, 256 thr (4 waves).
// Q pre-scaled by log2(e) -> e = exp2(s) directly; truncation bf16 packing.
__global__ __launch_bounds__(256, 2) void k_attn(
    const ushort* __restrict__ qg, const ushort* __restrict__ ktg,
    const ushort* __restrict__ vg,
    ushort* __restrict__ pacc, float* __restrict__ lpart)
{
    __shared__ ushort v_lds[2][16*512];   // 16 V frags (cfr*4+ks), 1KB each
    __shared__ ushort kt_lds[2][4*512];   // 4 Kt frags (kb*2+ks)

    int blk = blockIdx.x;
    int msid = blk & 3;
    int cs   = (blk >> 2) & 1;
    int qb   = (blk >> 3) & 15;
    int b    = blk >> 7;
    int t = threadIdx.x;
    int w = t >> 6, lane = t & 63;
    int l31 = lane & 31, h = lane >> 5;
    int qbase = qb*256 + w*64;
    int cbase = cs*128;
    int mbase = msid*1024;

    const ushort* kb_p = ktg + (size_t)b*HW_*C8_;
    const ushort* vb_p = vg  + (size_t)b*C_*HW_;

    // Q fragments (B-operand): lane l31 = q, regs = 8 consec e
    short8 qf[2][2];
    #pragma unroll
    for (int qfr = 0; qfr < 2; ++qfr)
        #pragma unroll
        for (int ks = 0; ks < 2; ++ks)
            qf[qfr][ks] = *(const short8*)(qg + ((size_t)b*HW_ + qbase + qfr*32 + l31)*C8_
                                           + ks*16 + h*8);

    f32x16 acc[2][4];
    #pragma unroll
    for (int i = 0; i < 2; ++i)
        #pragma unroll
        for (int j = 0; j < 4; ++j)
            acc[i][j] = (f32x16)(0.f);
    float lsum[2] = {0.f, 0.f};

    #define STAGE(buf, m0)                                                          \
    {                                                                               \
        _Pragma("unroll")                                                           \
        for (int ks = 0; ks < 4; ++ks) {                                            \
            const ushort* src = vb_p + (size_t)(cbase + w*32 + l31)*HW_             \
                                + (m0) + ks*16 + h*8;                               \
            __builtin_amdgcn_global_load_lds(                                       \
                (const __attribute__((address_space(1))) uint32_t*)src,             \
                (__attribute__((address_space(3))) uint32_t*)&v_lds[buf][(w*4+ks)*512], \
                16, 0, 0);                                                          \
        }                                                                           \
        {                                                                           \
            int kb = w >> 1, ks = w & 1;                                            \
            const ushort* src = kb_p + (size_t)((m0) + kb*32 + l31)*C8_             \
                                + ks*16 + h*8;                                      \
            __builtin_amdgcn_global_load_lds(                                       \
                (const __attribute__((address_space(1))) uint32_t*)src,             \
                (__attribute__((address_space(3))) uint32_t*)&kt_lds[buf][w*512],   \
                16, 0, 0);                                                          \
        }                                                                           \
    }

    STAGE(0, mbase)
    __syncthreads();

    int buf = 0;
    for (int it = 0; it < 16; ++it) {
        if (it + 1 < 16) STAGE(buf ^ 1, mbase + (it+1)*64)

        // Kt fragments for this chunk
        short8 ktf[2][2];
        #pragma unroll
        for (int kb = 0; kb < 2; ++kb)
            #pragma unroll
            for (int ks = 0; ks < 2; ++ks)
                ktf[kb][ks] = *(const short8*)(&kt_lds[buf][(kb*2+ks)*512 + lane*8]);

        // S tiles -> exp2 (L2E pre-folded) -> truncated bf16 pairs
        uint32_t up[4][8];   // [qfr*2+kb][8]
        #pragma unroll
        for (int qfr = 0; qfr < 2; ++qfr) {
            #pragma unroll
            for (int kb = 0; kb < 2; ++kb) {
                f32x16 s = (f32x16)(0.f);
                s = __builtin_amdgcn_mfma_f32_32x32x16_bf16(ktf[kb][0], qf[qfr][0], s, 0, 0, 0);
                s = __builtin_amdgcn_mfma_f32_32x32x16_bf16(ktf[kb][1], qf[qfr][1], s, 0, 0, 0);
                float e[16];
                #pragma unroll
                for (int r = 0; r < 16; ++r)
                    e[r] = __builtin_amdgcn_exp2f(s[r]);
                float2 tl2 = {0.f, 0.f};
                #pragma unroll
                for (int r = 0; r < 8; ++r) {
                    tl2.x += e[2*r];
                    tl2.y += e[2*r+1];
                }
                lsum[qfr] += tl2.x + tl2.y;
                #pragma unroll
                for (int i = 0; i < 8; ++i)
                    up[qfr*2+kb][i] = pktr(e[2*i], e[2*i+1]);
            }
        }

        // Build PV B-fragments: lane-half exchange
        short8 pf[2][4];   // [qfr][ks 0..3]
        #pragma unroll
        for (int qfr = 0; qfr < 2; ++qfr) {
            #pragma unroll
            for (int kb = 0; kb < 2; ++kb) {
                uint32_t* u = up[qfr*2+kb];
                uint32_t bpA = (uint32_t)__shfl_xor((int)(h ? u[0] : u[2]), 32);
                uint32_t bpB = (uint32_t)__shfl_xor((int)(h ? u[1] : u[3]), 32);
                uint32_t bpC = (uint32_t)__shfl_xor((int)(h ? u[4] : u[6]), 32);
                uint32_t bpD = (uint32_t)__shfl_xor((int)(h ? u[5] : u[7]), 32);
                union { uint32_t d[4]; short8 s8; } fe, fo;
                fe.d[0] = h ? bpA : u[0];  fe.d[1] = h ? bpB : u[1];
                fe.d[2] = h ? u[2] : bpA;  fe.d[3] = h ? u[3] : bpB;
                fo.d[0] = h ? bpC : u[4];  fo.d[1] = h ? bpD : u[5];
                fo.d[2] = h ? u[6] : bpC;  fo.d[3] = h ? u[7] : bpD;
                pf[qfr][kb*2 + 0] = fe.s8;
                pf[qfr][kb*2 + 1] = fo.s8;
            }
        }

        // PV: acc[qfr][cfr] += V(cfr,ks) * P(qfr,ks)
        #pragma unroll
        for (int ks = 0; ks < 4; ++ks) {
            #pragma unroll
            for (int cfr = 0; cfr < 4; ++cfr) {
                short8 vf = *(const short8*)(&v_lds[buf][(cfr*4+ks)*512 + lane*8]);
                acc[0][cfr] = __builtin_amdgcn_mfma_f32_32x32x16_bf16(vf, pf[0][ks], acc[0][cfr], 0, 0, 0);
                acc[1][cfr] = __builtin_amdgcn_mfma_f32_32x32x16_bf16(vf, pf[1][ks], acc[1][cfr], 0, 0, 0);
            }
        }
        __syncthreads();
        buf ^= 1;
    }

    // finalize l: add other lane-half's key contributions
    #pragma unroll
    for (int qfr = 0; qfr < 2; ++qfr) {
        union { float f; int i; } cv; cv.f = lsum[qfr];
        cv.i = __shfl_xor(cv.i, 32);
        lsum[qfr] += cv.f;
    }
    if (cs == 0 && h == 0) {
        #pragma unroll
        for (int qfr = 0; qfr < 2; ++qfr)
            lpart[(size_t)(msid*B_ + b)*HW_ + qbase + qfr*32 + l31] = lsum[qfr];
    }

    // store bf16 partial accumulators: [ms][b][c][q]
    #pragma unroll
    for (int qfr = 0; qfr < 2; ++qfr) {
        int q = qbase + qfr*32 + l31;
        #pragma unroll
        for (int cfr = 0; cfr < 4; ++cfr) {
            #pragma unroll
            for (int r = 0; r < 16; ++r) {
                int c = cbase + cfr*32 + (r & 3) + 8*(r >> 2) + 4*h;
                pacc[((size_t)(msid*B_ + b)*C_ + c)*HW_ + q] = f2bf(acc[qfr][cfr][r]);
            }
        }
    }
    #undef STAGE
}

// ---------------- kernel 4: combine partials + epilogue ----------------
__global__ __launch_bounds__(256) void k_comb(
    const ushort* __restrict__ pacc, const float* __restrict__ lpart,
    const float* __restrict__ x, const float* __restrict__ gamma_p,
    float* __restrict__ out)
{
    int gid = blockIdx.x * 256 + threadIdx.x;   // one thread = 8 elements
    int q8 = gid & 511;
    int c  = (gid >> 9) & 255;
    int b  = gid >> 17;
    size_t base = ((size_t)b*C_ + c)*HW_ + q8*8;

    float sum[8];
    #pragma unroll
    for (int k = 0; k < 8; ++k) sum[k] = 0.f;
    float lt[8];
    #pragma unroll
    for (int k = 0; k < 8; ++k) lt[k] = 0.f;

    #pragma unroll
    for (int ms = 0; ms < MS_; ++ms) {
        const ushort* pp = pacc + ((size_t)(ms*B_ + b)*C_ + c)*HW_ + q8*8;
        us8 v = *(const us8*)pp;
        #pragma unroll
        for (int k = 0; k < 8; ++k) {
            union { uint32_t u; float f; } cv; cv.u = ((uint32_t)v[k]) << 16;
            sum[k] += cv.f;
        }
        const float* lp = lpart + (size_t)(ms*B_ + b)*HW_ + q8*8;
        float4 l0 = *(const float4*)lp;
        float4 l1 = *(const float4*)(lp + 4);
        lt[0] += l0.x; lt[1] += l0.y; lt[2] += l0.z; lt[3] += l0.w;
        lt[4] += l1.x; lt[5] += l1.y; lt[6] += l1.z; lt[7] += l1.w;
    }

    float g = gamma_p[0];
    float4 x0 = *(const float4*)(x + base);
    float4 x1 = *(const float4*)(x + base + 4);
    float4 o0, o1;
    o0.x = g*sum[0]/lt[0] + x0.x;  o0.y = g*sum[1]/lt[1] + x0.y;
    o0.z = g*sum[2]/lt[2] + x0.z;  o0.w = g*sum[3]/lt[3] + x0.w;
    o1.x = g*sum[4]/lt[4] + x1.x;  o1.y = g*sum[5]/lt[5] + x1.y;
    o1.z = g*sum[6]/lt[6] + x1.z;  o1.w = g*sum[7]/lt[7] + x1.w;
    *(float4*)(out + base)     = o0;
    *(float4*)(out + base + 4) = o1;
}

extern "C" void kernel_launch(void* const* d_in, const int* in_sizes, int n_in,
                              void* d_out, int out_size, void* d_ws, size_t ws_size,
                              hipStream_t stream)
{
    const float* x      = (const float*)d_in[0];
    const float* conv_w = (const float*)d_in[1];
    const float* conv_b = (const float*)d_in[2];
    const float* q_w    = (const float*)d_in[3];
    const float* q_b    = (const float*)d_in[4];
    const float* k_w    = (const float*)d_in[5];
    const float* k_b    = (const float*)d_in[6];
    const float* v_w    = (const float*)d_in[7];
    const float* v_b    = (const float*)d_in[8];
    const float* gamma  = (const float*)d_in[9];
    float* out = (float*)d_out;

    char* ws = (char*)d_ws;
    ushort* wbf   = (ushort*)(ws + WT_OFF);
    float*  ball  = (float*)(ws + BALL_OFF);
    ushort* qg    = (ushort*)(ws + Q_OFF);
    ushort* ktg   = (ushort*)(ws + KT_OFF);
    ushort* vg    = (ushort*)(ws + V_OFF);
    ushort* pacc  = (ushort*)(ws + PACC_OFF);
    float*  lpart = (float*)(ws + LPART_OFF);

    k_setup<<<ROWS_, 256, 0, stream>>>(conv_w, conv_b, q_w, q_b, k_w, k_b,
                                       v_w, v_b, wbf, ball);
    k_qkv<<<B_*64, 320, 0, stream>>>(x, wbf, ball, qg, ktg, vg);
    k_attn<<<512, 256, 0, stream>>>(qg, ktg, vg, pacc, lpart);
    k_comb<<<(B_*C_*HW_/8 + 255)/256, 256, 0, stream>>>(pacc, lpart, x, gamma, out);
}